// Round 7
// baseline (3005.062 us; speedup 1.0000x reference)
//
#include <hip/hip_runtime.h>
#include <math.h>

#define Hn 50
#define Dn 8
#define Tn 512
#define BB 4            // batch rows per block
#define KC 13           // k-chunk per wave (4 waves x 13 = 52 >= 50)
#define NBLK (2048 / BB)

__device__ __forceinline__ float sigmoidf_(float x) {
    return 1.0f / (1.0f + __expf(-x));
}
__device__ __forceinline__ float tanhf_(float x) {
    float a = fabsf(x);
    float e = __expf(-2.0f * a);
    float r = (1.0f - e) / (1.0f + e);
    return copysignf(r, x);
}
__device__ __forceinline__ float rlane(float v, int l) {
    return __int_as_float(__builtin_amdgcn_readlane(__float_as_int(v), l));
}

// Persistent 2-layer LSTM, readlane-distributed h (round-6 skeleton).
// Round-6 fit 240 live values into a 168-VGPR allocation -> the compiler
// parked weights in AGPRs and every access paid a v_accvgpr copy (~5000
// extra VALU cyc/step). This round trims true liveness to ~210 so the
// __launch_bounds__(256,1) 256-reg budget holds everything in ArchVGPRs:
//  - x loaded straight from global each step (same line across the wave,
//    L1/L3 resident; consumed at END of phase A -> ~600 cyc latency window)
//  - h1 tile re-read from LDS in phase C instead of carried from phase A
//  - one acc[4][4] per matvec phase, dead at its gP store.
__global__ __launch_bounds__(256, 1) void lstm2_kernel(
    const float* __restrict__ x,
    const float* __restrict__ Wih0, const float* __restrict__ Whh0,
    const float* __restrict__ bih0, const float* __restrict__ bhh0,
    const float* __restrict__ Wih1, const float* __restrict__ Whh1,
    const float* __restrict__ bih1, const float* __restrict__ bhh1,
    const float* __restrict__ Wlin, const float* __restrict__ blin,
    float* __restrict__ out)
{
    const int tid  = threadIdx.x;       // 0..255
    const int b0   = blockIdx.x * BB;
    const int w    = tid >> 6;          // wave index -> k-chunk
    const int lane = tid & 63;          // cell owned by this lane
    const int kb   = w * KC;            // chunk base
    const bool realc = (lane < Hn);

    // LDS: h tiles (slot k*4+b holds h[k][b]; padded to 256 floats so the
    // b128 tile read at lanes 50..63 stays in-bounds), gate partials
    // gP[w][g][cell][b] (b128 writes lane-stride-16B, act reads stride-4B).
    __shared__ __align__(16) float h0s[256];
    __shared__ __align__(16) float h1s[256];
    __shared__ __align__(16) float gP[4][4][64][4];

    // ---- weight slices in registers (164 floats, persistent) ----
    float wa[4][KC], wb[4][KC], wc[4][KC], wx[4][2];
    #pragma unroll
    for (int g = 0; g < 4; ++g) {
        const int row = g * Hn + lane;          // valid iff realc
        #pragma unroll
        for (int j = 0; j < KC; ++j) {
            const int k = kb + j;
            const bool ok = realc && (k < Hn);
            wa[g][j] = ok ? Whh0[row * Hn + k] : 0.f;
            wb[g][j] = ok ? Wih1[row * Hn + k] : 0.f;
            wc[g][j] = ok ? Whh1[row * Hn + k] : 0.f;
        }
        #pragma unroll
        for (int d = 0; d < 2; ++d)
            wx[g][d] = realc ? Wih0[row * Dn + 2 * w + d] : 0.f;
    }

    // ---- activation mapping: tid<200 owns state (cell=tid>>2, b=tid&3) ----
    const int cA = tid >> 2, bA = tid & 3;
    const bool actT = (tid < Hn * BB);
    float bs0[4], bs1[4];
    #pragma unroll
    for (int g = 0; g < 4; ++g) {
        bs0[g] = actT ? (bih0[g * Hn + cA] + bhh0[g * Hn + cA]) : 0.f;
        bs1[g] = actT ? (bih1[g * Hn + cA] + bhh1[g * Hn + cA]) : 0.f;
    }
    float c0 = 0.f, c1 = 0.f;

    // zero h tiles (incl. pads read by the wide tile loads)
    h0s[tid] = 0.f;
    h1s[tid] = 0.f;
    __syncthreads();

    // per-wave x column base: d in {2w, 2w+1}
    const float* xwp = x + 2 * w;

    for (int t = 0; t < Tn; ++t) {
        // ---- issue x_t loads first (consumed at end of phase A) ----
        float2 xv[BB];
        #pragma unroll
        for (int b = 0; b < BB; ++b)
            xv[b] = *(const float2*)(xwp + ((size_t)(b0 + b) * Tn + t) * Dn);

        // ---- phase A: acc = Whh0.h0 (k-chunk partials), then + Wih0.x ----
        const float4 h0t = *(const float4*)&h0s[lane * 4];   // whole tile
        float acc[4][BB];
        #pragma unroll
        for (int g = 0; g < 4; ++g)
            #pragma unroll
            for (int b = 0; b < BB; ++b) acc[g][b] = 0.f;
        #pragma unroll
        for (int j = 0; j < KC; ++j) {
            const int kl = kb + j;
            const float hv0 = rlane(h0t.x, kl);
            const float hv1 = rlane(h0t.y, kl);
            const float hv2 = rlane(h0t.z, kl);
            const float hv3 = rlane(h0t.w, kl);
            #pragma unroll
            for (int g = 0; g < 4; ++g) {
                acc[g][0] += wa[g][j] * hv0;
                acc[g][1] += wa[g][j] * hv1;
                acc[g][2] += wa[g][j] * hv2;
                acc[g][3] += wa[g][j] * hv3;
            }
        }
        #pragma unroll
        for (int g = 0; g < 4; ++g)
            #pragma unroll
            for (int b = 0; b < BB; ++b)
                acc[g][b] += wx[g][0] * xv[b].x + wx[g][1] * xv[b].y;
        #pragma unroll
        for (int g = 0; g < 4; ++g)
            *(float4*)&gP[w][g][lane][0] =
                make_float4(acc[g][0], acc[g][1], acc[g][2], acc[g][3]);
        __syncthreads();

        // ---- phase B: layer-0 activations ----
        if (actT) {
            float gv[4];
            #pragma unroll
            for (int g = 0; g < 4; ++g)
                gv[g] = gP[0][g][cA][bA] + gP[1][g][cA][bA]
                      + gP[2][g][cA][bA] + gP[3][g][cA][bA] + bs0[g];
            const float iv = sigmoidf_(gv[0]);
            const float fv = sigmoidf_(gv[1]);
            const float gg = tanhf_(gv[2]);
            const float ov = sigmoidf_(gv[3]);
            c0 = fv * c0 + iv * gg;
            h0s[tid] = ov * tanhf_(c0);     // tile slot (cA*4+bA) == tid
        }
        __syncthreads();

        // ---- phase C: acc = Wih1.h0new + Whh1.h1old ----
        const float4 h0nt = *(const float4*)&h0s[lane * 4];
        const float4 h1t  = *(const float4*)&h1s[lane * 4]; // unchanged since D(t-1)
        float acc2[4][BB];
        #pragma unroll
        for (int g = 0; g < 4; ++g)
            #pragma unroll
            for (int b = 0; b < BB; ++b) acc2[g][b] = 0.f;
        #pragma unroll
        for (int j = 0; j < KC; ++j) {
            const int kl = kb + j;
            const float nv0 = rlane(h0nt.x, kl);
            const float nv1 = rlane(h0nt.y, kl);
            const float nv2 = rlane(h0nt.z, kl);
            const float nv3 = rlane(h0nt.w, kl);
            const float ov0 = rlane(h1t.x, kl);
            const float ov1 = rlane(h1t.y, kl);
            const float ov2 = rlane(h1t.z, kl);
            const float ov3 = rlane(h1t.w, kl);
            #pragma unroll
            for (int g = 0; g < 4; ++g) {
                acc2[g][0] += wb[g][j] * nv0 + wc[g][j] * ov0;
                acc2[g][1] += wb[g][j] * nv1 + wc[g][j] * ov1;
                acc2[g][2] += wb[g][j] * nv2 + wc[g][j] * ov2;
                acc2[g][3] += wb[g][j] * nv3 + wc[g][j] * ov3;
            }
        }
        #pragma unroll
        for (int g = 0; g < 4; ++g)
            *(float4*)&gP[w][g][lane][0] =
                make_float4(acc2[g][0], acc2[g][1], acc2[g][2], acc2[g][3]);
        __syncthreads();

        // ---- phase D: layer-1 activations ----
        if (actT) {
            float gv[4];
            #pragma unroll
            for (int g = 0; g < 4; ++g)
                gv[g] = gP[0][g][cA][bA] + gP[1][g][cA][bA]
                      + gP[2][g][cA][bA] + gP[3][g][cA][bA] + bs1[g];
            const float iv = sigmoidf_(gv[0]);
            const float fv = sigmoidf_(gv[1]);
            const float gg = tanhf_(gv[2]);
            const float ov = sigmoidf_(gv[3]);
            c1 = fv * c1 + iv * gg;
            h1s[tid] = ov * tanhf_(c1);
        }
        __syncthreads();
    }

    // ---- head: out[b] = h1_last . Wlin + blin ----
    if (tid < BB) {
        float o = blin[0];
        #pragma unroll
        for (int k = 0; k < Hn; ++k) o += Wlin[k] * h1s[k * 4 + tid];
        out[b0 + tid] = o;
    }
}

extern "C" void kernel_launch(void* const* d_in, const int* in_sizes, int n_in,
                              void* d_out, int out_size, void* d_ws, size_t ws_size,
                              hipStream_t stream) {
    const float* x    = (const float*)d_in[0];
    const float* Wih0 = (const float*)d_in[1];
    const float* Whh0 = (const float*)d_in[2];
    const float* bih0 = (const float*)d_in[3];
    const float* bhh0 = (const float*)d_in[4];
    const float* Wih1 = (const float*)d_in[5];
    const float* Whh1 = (const float*)d_in[6];
    const float* bih1 = (const float*)d_in[7];
    const float* bhh1 = (const float*)d_in[8];
    const float* Wlin = (const float*)d_in[9];
    const float* blin = (const float*)d_in[10];
    float* out = (float*)d_out;

    lstm2_kernel<<<NBLK, 256, 0, stream>>>(x, Wih0, Whh0, bih0, bhh0,
                                           Wih1, Whh1, bih1, bhh1,
                                           Wlin, blin, out);
}